// Round 7
// baseline (2402.154 us; speedup 1.0000x reference)
//
#include <hip/hip_runtime.h>
#include <math.h>

// ---------------------------------------------------------------------------
// APPNP + 3-layer GCN on MI355X.
// Round 7 changes:
//  (a) Non-temporal hints on ALL streaming traffic (edge lists, SpMM output
//      stores, GEMM A-reads, z0/logsm I/O) so the 256 MB L3 is reserved for
//      the SpMM gather-hot h buffer. Theory: L3 hit rate on gathers was only
//      ~54% (784 MB HBM fetch vs 50 MB source) due to stream pollution.
//  (b) spmm_relu gather unroll 4 -> 8 (more outstanding random requests).
//  (c) k_init_cnt removed (memsetAsync + deg = cnt+1 at use sites).
// Carried: fp16 h buffers, MFMA fp16 GEMM, APPNP commuted with final
// projection (40-dim propagate, 128 B padded rows, 2 rows/wave), atomic
// segment-alloc CSR (no scan).
// ---------------------------------------------------------------------------

constexpr int D  = 256;   // feature / hidden dim
constexpr int C  = 40;    // classes
constexpr int ZP = 64;    // padded z row (fp16 elems) = 128 B

typedef _Float16 h2v    __attribute__((ext_vector_type(2)));
typedef _Float16 h4     __attribute__((ext_vector_type(4)));
typedef _Float16 half8v __attribute__((ext_vector_type(8)));
typedef float    f32x4  __attribute__((ext_vector_type(4)));

struct __align__(8) EdgeCV { int c; float v; };

// ---- non-temporal helpers -------------------------------------------------

__device__ inline EdgeCV nt_edge(const EdgeCV* p) {
    unsigned long long u = __builtin_nontemporal_load((const unsigned long long*)p);
    EdgeCV e;
    e.c = (int)(unsigned)(u & 0xffffffffull);
    e.v = __uint_as_float((unsigned)(u >> 32));
    return e;
}
__device__ inline void nt_store_edge(EdgeCV* p, EdgeCV e) {
    unsigned long long u = ((unsigned long long)__float_as_uint(e.v) << 32) |
                           (unsigned long long)(unsigned)e.c;
    __builtin_nontemporal_store(u, (unsigned long long*)p);
}
__device__ inline half8v nt_load_h8(const _Float16* p) {
    f32x4 f = __builtin_nontemporal_load((const f32x4*)p);
    return __builtin_bit_cast(half8v, f);
}
__device__ inline f32x4 nt_load_f4(const float* p) {
    return __builtin_nontemporal_load((const f32x4*)p);
}
__device__ inline void nt_store_h4(h4* p, h4 v) {
    __builtin_nontemporal_store(__builtin_bit_cast(unsigned long long, v),
                                (unsigned long long*)p);
}
__device__ inline h2v nt_load_h2(const h2v* p) {
    unsigned u = __builtin_nontemporal_load((const unsigned*)p);
    return __builtin_bit_cast(h2v, u);
}

// ---- CSR build (order-free segment alloc; cnt counts real in-edges) -------

__global__ void k_count(const int* __restrict__ dst, int* __restrict__ cnt, int E) {
    int e = blockIdx.x * blockDim.x + threadIdx.x;
    if (e < E) {
        int d = __builtin_nontemporal_load(dst + e);
        atomicAdd(&cnt[d], 1);
    }
}

__global__ void k_alloc(const int* __restrict__ cnt, int* __restrict__ startA,
                        int* __restrict__ cursor, int N) {
    int i = blockIdx.x * blockDim.x + threadIdx.x;
    if (i < N) startA[i] = atomicAdd(cursor, cnt[i] + 1);   // +1 self loop
}

// dinv + self-loop edge + fill-counter init, one pass
__global__ void k_selfinit(const int* __restrict__ cnt, const int* __restrict__ startA,
                           float* __restrict__ dinv, EdgeCV* __restrict__ edges,
                           int* __restrict__ fill, int N) {
    int i = blockIdx.x * blockDim.x + threadIdx.x;
    if (i < N) {
        float dv = rsqrtf((float)(cnt[i] + 1));
        dinv[i] = dv;
        EdgeCV e; e.c = i; e.v = dv * dv;
        nt_store_edge(&edges[startA[i]], e);
        fill[i] = 1;
    }
}

__global__ void k_fill_edges(const int* __restrict__ src, const int* __restrict__ dst,
                             const int* __restrict__ startA, const float* __restrict__ dinv,
                             EdgeCV* __restrict__ edges, int* __restrict__ fill, int E) {
    int e = blockIdx.x * blockDim.x + threadIdx.x;
    if (e < E) {
        int s = __builtin_nontemporal_load(src + e);
        int d = __builtin_nontemporal_load(dst + e);
        int slot = atomicAdd(&fill[d], 1);
        EdgeCV ev; ev.c = s; ev.v = dinv[s] * dinv[d];
        nt_store_edge(&edges[startA[d] + slot], ev);
    }
}

// ---- W transpose: W[k][n] fp32 -> Wt[w][n][k] fp16 (3 x 256 x 256) --------

__global__ void k_transW(const float* __restrict__ W0, const float* __restrict__ W1,
                         const float* __restrict__ W2, _Float16* __restrict__ Wt) {
    int n = blockIdx.x;
    int w = blockIdx.y;
    int k = threadIdx.x;
    const float* W = (w == 0) ? W0 : (w == 1) ? W1 : W2;
    Wt[(size_t)w * 65536 + n * 256 + k] = (_Float16)W[k * 256 + n];
}

// ---- MFMA GEMM: Cout_fp16[M x 256] = A[M x 256] @ W (via Wt[n][k] fp16) ---
// block = 256 threads (4 waves), 128 rows/block, full N=256, fp32 accumulate.
// A-reads are read-once -> non-temporal. Cout is the next SpMM's gather
// source -> cacheable stores.

template <typename TIN>
__global__ __launch_bounds__(256, 1) void k_gemm_mfma(const TIN* __restrict__ A,
                                                      const _Float16* __restrict__ Wt,
                                                      _Float16* __restrict__ Cout, int M) {
    __shared__ _Float16 wlds[256][72];   // n-major K-strip of 64 (+8 pad)
    const int tid  = threadIdx.x;
    const int lane = tid & 63;
    const int wave = tid >> 6;
    const int l15  = lane & 15;
    const int lk8  = (lane >> 4) * 8;
    const int rowbase = blockIdx.x * 128 + wave * 32;

    half8v a[2][8];
    #pragma unroll
    for (int mt = 0; mt < 2; ++mt) {
        int row = rowbase + mt * 16 + l15;
        bool ok = row < M;
        const TIN* ap = A + (size_t)(ok ? row : 0) * D;
        #pragma unroll
        for (int kk = 0; kk < 8; ++kk) {
            half8v v;
            if constexpr (sizeof(TIN) == 2) {
                v = nt_load_h8((const _Float16*)(ap + kk * 32 + lk8));
            } else {
                f32x4 f0 = nt_load_f4((const float*)(ap + kk * 32 + lk8));
                f32x4 f1 = nt_load_f4((const float*)(ap + kk * 32 + lk8 + 4));
                v[0] = (_Float16)f0[0]; v[1] = (_Float16)f0[1];
                v[2] = (_Float16)f0[2]; v[3] = (_Float16)f0[3];
                v[4] = (_Float16)f1[0]; v[5] = (_Float16)f1[1];
                v[6] = (_Float16)f1[2]; v[7] = (_Float16)f1[3];
            }
            if (!ok) {
                half8v zz = {0, 0, 0, 0, 0, 0, 0, 0};
                v = zz;
            }
            a[mt][kk] = v;
        }
    }

    f32x4 acc[2][16] = {};

    #pragma unroll
    for (int s = 0; s < 4; ++s) {       // K strips of 64
        {
            const half8v* srcp = (const half8v*)(Wt + (size_t)tid * D + s * 64);
            #pragma unroll
            for (int cc = 0; cc < 8; ++cc)
                *(half8v*)(&wlds[tid][cc * 8]) = srcp[cc];
        }
        __syncthreads();
        #pragma unroll
        for (int kf = 0; kf < 2; ++kf) {
            const int kk = s * 2 + kf;
            #pragma unroll
            for (int nt = 0; nt < 16; ++nt) {
                half8v b = *(const half8v*)(&wlds[nt * 16 + l15][kf * 32 + lk8]);
                acc[0][nt] = __builtin_amdgcn_mfma_f32_16x16x32_f16(a[0][kk], b, acc[0][nt], 0, 0, 0);
                acc[1][nt] = __builtin_amdgcn_mfma_f32_16x16x32_f16(a[1][kk], b, acc[1][nt], 0, 0, 0);
            }
        }
        __syncthreads();
    }

    const int r0 = (lane >> 4) * 4;
    #pragma unroll
    for (int mt = 0; mt < 2; ++mt) {
        #pragma unroll
        for (int r = 0; r < 4; ++r) {
            int row = rowbase + mt * 16 + r0 + r;
            if (row < M) {
                _Float16* crow = Cout + (size_t)row * D;
                #pragma unroll
                for (int nt = 0; nt < 16; ++nt)
                    crow[nt * 16 + l15] = (_Float16)acc[mt][nt][r];
            }
        }
    }
}

// ---- SpMM 256-dim (GCN): out = relu(sum_e v*h[col] + bias), wave/row ------
// h gathers cacheable (the L3-hot data); edges NT; out NT (next reader
// streams it once).

__global__ __launch_bounds__(256) void k_spmm_relu(const _Float16* __restrict__ h,
                                                   const int* __restrict__ startA,
                                                   const int* __restrict__ cnt,
                                                   const EdgeCV* __restrict__ edges,
                                                   const float* __restrict__ bias,
                                                   _Float16* __restrict__ out, int N) {
    int gid  = (int)((blockIdx.x * 256u + threadIdx.x) >> 6);
    int lane = threadIdx.x & 63;
    if (gid >= N) return;
    int start = startA[gid], end = start + cnt[gid] + 1;
    const h4* hp = (const h4*)h;
    float4 s[8];
    #pragma unroll
    for (int i = 0; i < 8; ++i) s[i] = make_float4(0.f, 0.f, 0.f, 0.f);
    int e = start;
    for (; e + 7 < end; e += 8) {        // 8 independent gathers in flight
        EdgeCV c[8];
        h4 x[8];
        #pragma unroll
        for (int i = 0; i < 8; ++i) c[i] = nt_edge(&edges[e + i]);
        #pragma unroll
        for (int i = 0; i < 8; ++i) x[i] = hp[(size_t)c[i].c * 64 + lane];
        #pragma unroll
        for (int i = 0; i < 8; ++i) {
            s[i].x += c[i].v * (float)x[i][0];
            s[i].y += c[i].v * (float)x[i][1];
            s[i].z += c[i].v * (float)x[i][2];
            s[i].w += c[i].v * (float)x[i][3];
        }
    }
    for (; e < end; ++e) {
        EdgeCV c0 = nt_edge(&edges[e]);
        h4 x0 = hp[(size_t)c0.c * 64 + lane];
        s[0].x += c0.v * (float)x0[0]; s[0].y += c0.v * (float)x0[1];
        s[0].z += c0.v * (float)x0[2]; s[0].w += c0.v * (float)x0[3];
    }
    float4 acc = make_float4(0.f, 0.f, 0.f, 0.f);
    #pragma unroll
    for (int i = 0; i < 8; ++i) {
        acc.x += s[i].x; acc.y += s[i].y; acc.z += s[i].z; acc.w += s[i].w;
    }
    float4 b = ((const float4*)bias)[lane];
    h4 o;
    o[0] = (_Float16)fmaxf(acc.x + b.x, 0.f);
    o[1] = (_Float16)fmaxf(acc.y + b.y, 0.f);
    o[2] = (_Float16)fmaxf(acc.z + b.z, 0.f);
    o[3] = (_Float16)fmaxf(acc.w + b.w, 0.f);
    nt_store_h4((h4*)out + (size_t)gid * 64 + lane, o);
}

// ---- projection z0 = h0 @ fc_w (N x 40), padded to ZP, fp32 acc -----------

__global__ __launch_bounds__(256) void k_z0(const _Float16* __restrict__ h,
                                            const float* __restrict__ fcw,
                                            _Float16* __restrict__ z0, int N) {
    __shared__ float ws[D * C];          // 40 KB
    for (int i = threadIdx.x; i < D * C; i += 256) ws[i] = fcw[i];
    __syncthreads();
    int row = blockIdx.x * 256 + threadIdx.x;
    if (row >= N) return;
    float acc[C] = {};
    const _Float16* hr = h + (size_t)row * D;
    for (int kq = 0; kq < 32; ++kq) {
        half8v v = nt_load_h8(hr + kq * 8);
        #pragma unroll
        for (int j = 0; j < 8; ++j) {
            float hv = (float)v[j];
            #pragma unroll
            for (int c = 0; c < C; ++c) acc[c] += hv * ws[(kq * 8 + j) * C + c];
        }
    }
    h2v* zr = (h2v*)(z0 + (size_t)row * ZP);
    #pragma unroll
    for (int c = 0; c < 20; ++c) {
        h2v o; o[0] = (_Float16)acc[2 * c]; o[1] = (_Float16)acc[2 * c + 1];
        zr[c] = o;
    }
    h2v zz = {(_Float16)0.f, (_Float16)0.f};
    #pragma unroll
    for (int c = 20; c < 32; ++c) zr[c] = zz;   // zero the pad
}

// ---- SpMM 40-dim padded (APPNP): 2 rows/wave, 32 lanes x 4B = 1 line ------
// out = 0.9*sum_e v*z[col] + 0.1*z0   (pad columns stay zero)

__global__ __launch_bounds__(256) void k_spmm40(const _Float16* __restrict__ z,
                                                const int* __restrict__ startA,
                                                const int* __restrict__ cnt,
                                                const EdgeCV* __restrict__ edges,
                                                const _Float16* __restrict__ z0,
                                                _Float16* __restrict__ out, int N) {
    int wid  = (int)((blockIdx.x * 256u + threadIdx.x) >> 6);
    int lane = threadIdx.x & 63;
    int p    = lane >> 5;                 // half-wave -> row parity
    int l5   = lane & 31;
    int row  = wid * 2 + p;
    if (row >= N) return;
    int start = startA[row], end = start + cnt[row] + 1;
    const h2v* zp = (const h2v*)z;        // row stride ZP/2 = 32 h2v
    float ax0 = 0.f, ay0 = 0.f, ax1 = 0.f, ay1 = 0.f;
    float ax2 = 0.f, ay2 = 0.f, ax3 = 0.f, ay3 = 0.f;
    int e = start;
    for (; e + 3 < end; e += 4) {
        EdgeCV c0 = nt_edge(&edges[e]);
        EdgeCV c1 = nt_edge(&edges[e + 1]);
        EdgeCV c2 = nt_edge(&edges[e + 2]);
        EdgeCV c3 = nt_edge(&edges[e + 3]);
        h2v x0 = zp[(size_t)c0.c * 32 + l5];
        h2v x1 = zp[(size_t)c1.c * 32 + l5];
        h2v x2 = zp[(size_t)c2.c * 32 + l5];
        h2v x3 = zp[(size_t)c3.c * 32 + l5];
        ax0 += c0.v * (float)x0[0]; ay0 += c0.v * (float)x0[1];
        ax1 += c1.v * (float)x1[0]; ay1 += c1.v * (float)x1[1];
        ax2 += c2.v * (float)x2[0]; ay2 += c2.v * (float)x2[1];
        ax3 += c3.v * (float)x3[0]; ay3 += c3.v * (float)x3[1];
    }
    for (; e < end; ++e) {
        EdgeCV c0 = nt_edge(&edges[e]);
        h2v x0 = zp[(size_t)c0.c * 32 + l5];
        ax0 += c0.v * (float)x0[0]; ay0 += c0.v * (float)x0[1];
    }
    float ax = ax0 + ax1 + ax2 + ax3;
    float ay = ay0 + ay1 + ay2 + ay3;
    h2v zz = ((const h2v*)z0)[(size_t)row * 32 + l5];
    ax = 0.9f * ax + 0.1f * (float)zz[0];
    ay = 0.9f * ay + 0.1f * (float)zz[1];
    h2v o; o[0] = (_Float16)ax; o[1] = (_Float16)ay;
    ((h2v*)out)[(size_t)row * 32 + l5] = o;
}

// ---- final: out = log_softmax(z + fcb) ------------------------------------

__global__ __launch_bounds__(256) void k_logsm(const _Float16* __restrict__ z,
                                               const float* __restrict__ fcb,
                                               float* __restrict__ out, int N) {
    __shared__ float bs[C];
    for (int i = threadIdx.x; i < C; i += 256) bs[i] = fcb[i];
    __syncthreads();
    int row = blockIdx.x * 256 + threadIdx.x;
    if (row >= N) return;
    float v[C];
    const h2v* zr = (const h2v*)(z + (size_t)row * ZP);
    #pragma unroll
    for (int c = 0; c < 20; ++c) {
        h2v t = nt_load_h2(zr + c);
        v[2 * c]     = (float)t[0] + bs[2 * c];
        v[2 * c + 1] = (float)t[1] + bs[2 * c + 1];
    }
    float m = v[0];
    #pragma unroll
    for (int c = 1; c < C; ++c) m = fmaxf(m, v[c]);
    float s = 0.f;
    #pragma unroll
    for (int c = 0; c < C; ++c) s += expf(v[c] - m);
    float lse = logf(s) + m;
    float* orow = out + (size_t)row * C;
    #pragma unroll
    for (int c = 0; c < C; ++c)
        __builtin_nontemporal_store(v[c] - lse, orow + c);
}

// ---------------------------------------------------------------------------

extern "C" void kernel_launch(void* const* d_in, const int* in_sizes, int n_in,
                              void* d_out, int out_size, void* d_ws, size_t ws_size,
                              hipStream_t stream) {
    const float* x   = (const float*)d_in[0];
    const int*   ei  = (const int*)d_in[1];
    const float* w1  = (const float*)d_in[2];
    const float* b1  = (const float*)d_in[3];
    const float* w2  = (const float*)d_in[4];
    const float* b2  = (const float*)d_in[5];
    const float* w3  = (const float*)d_in[6];
    const float* b3  = (const float*)d_in[7];
    const float* fcw = (const float*)d_in[8];
    const float* fcb = (const float*)d_in[9];
    float* out = (float*)d_out;

    const int N = in_sizes[0] / D;
    const int E = in_sizes[1] / 2;
    const int* srcArr = ei;
    const int* dstArr = ei + E;

    char* wsp = (char*)d_ws;
    size_t off = 0;
    auto take = [&](size_t bytes) -> void* {
        void* p = wsp + off;
        off = (off + bytes + 255) & ~(size_t)255;
        return p;
    };
    int*       cnt    = (int*)take((size_t)N * 4);
    int*       startA = (int*)take((size_t)N * 4);
    int*       fill   = (int*)take((size_t)N * 4);
    int*       cursor = (int*)take(256);
    float*     dinv   = (float*)take((size_t)N * 4);
    EdgeCV*    edges  = (EdgeCV*)take((size_t)(E + N) * 8);
    _Float16*  bufA   = (_Float16*)take((size_t)N * D * 2);
    _Float16*  bufB   = (_Float16*)take((size_t)N * D * 2);
    _Float16*  bufC   = (_Float16*)take((size_t)N * D * 2);
    _Float16*  Wt     = (_Float16*)take((size_t)3 * D * D * 2);
    _Float16*  z0w    = (_Float16*)take((size_t)N * ZP * 2);
    _Float16*  zA     = (_Float16*)take((size_t)N * ZP * 2);
    _Float16*  zB     = (_Float16*)take((size_t)N * ZP * 2);
    (void)ws_size;

    dim3 b256(256);
    int gN = (N + 255) / 256;
    int gE = (E + 255) / 256;

    // CSR build (order-free segment allocation, no scan)
    hipMemsetAsync(cursor, 0, 4, stream);
    hipMemsetAsync(cnt, 0, (size_t)N * 4, stream);
    k_count<<<gE, b256, 0, stream>>>(dstArr, cnt, E);
    k_alloc<<<gN, b256, 0, stream>>>(cnt, startA, cursor, N);
    k_selfinit<<<gN, b256, 0, stream>>>(cnt, startA, dinv, edges, fill, N);
    k_fill_edges<<<gE, b256, 0, stream>>>(srcArr, dstArr, startA, dinv, edges, fill, E);

    // weight transposes (fp32 -> fp16, n-major), all three at once
    dim3 tg(256, 3);
    k_transW<<<tg, b256, 0, stream>>>(w1, w2, w3, Wt);

    dim3 gg((N + 127) / 128);
    int spBlocks   = (N + 3) / 4;      // wave per row (256-dim)
    int sp40Blocks = (N + 7) / 8;      // 2 rows per wave (40-dim padded)

    // GCN layers (bias+relu fused into SpMM epilogue)
    k_gemm_mfma<float><<<gg, b256, 0, stream>>>(x, Wt, bufA, N);
    k_spmm_relu<<<spBlocks, b256, 0, stream>>>(bufA, startA, cnt, edges, b1, bufB, N);
    k_gemm_mfma<_Float16><<<gg, b256, 0, stream>>>(bufB, Wt + 65536, bufA, N);
    k_spmm_relu<<<spBlocks, b256, 0, stream>>>(bufA, startA, cnt, edges, b2, bufB, N);
    k_gemm_mfma<_Float16><<<gg, b256, 0, stream>>>(bufB, Wt + 131072, bufA, N);
    k_spmm_relu<<<spBlocks, b256, 0, stream>>>(bufA, startA, cnt, edges, b3, bufC, N);  // h0

    // project: z0 = h0 @ fc_w  (bias added at the end), padded rows
    k_z0<<<gN, b256, 0, stream>>>(bufC, fcw, z0w, N);

    // APPNP on padded 40-dim z: z <- 0.9 * A_hat z + 0.1 * z0
    const _Float16* zc = z0w;
    _Float16* zn = zA;
    for (int it = 0; it < 10; ++it) {
        k_spmm40<<<sp40Blocks, b256, 0, stream>>>(zc, startA, cnt, edges, z0w, zn, N);
        zc = zn;
        zn = (zn == zA) ? zB : zA;
    }

    // final: log_softmax(z + fcb)
    k_logsm<<<gN, b256, 0, stream>>>(zc, fcb, out, N);
}

// Round 8
// 2114.643 us; speedup vs baseline: 1.1360x; 1.1360x over previous
//
#include <hip/hip_runtime.h>
#include <math.h>

// ---------------------------------------------------------------------------
// APPNP + 3-layer GCN on MI355X.
// Round 8:
//  (a) REVERT r7 regressions (NT hints removed, spmm_relu back to 4-unroll /
//      VGPR-28 / 80% occupancy form that measured 227 us).
//  (b) EXPERIMENT: layer-1 SpMM sliced by feature (t1 slice-major [4][N][64],
//      grid-y = slice, 1 row/wave/slice, 1 x 128B line per edge-gather from a
//      12.5 MB hot set). FETCH_SIZE of this dispatch discriminates the
//      "47% policy / line-rate ceiling" model vs cache-capacity model.
//  (c) CSR: k_count records per-edge slot (eslot) -> fill kernel has NO
//      atomics; selfinit merged into alloc.
//  (d) spmm40 unroll 4 -> 8 (latency-bound: only 50K waves).
// Carried: fp16 h buffers, MFMA fp16 GEMM, APPNP commuted with final
// projection (40-dim propagate, 128B padded rows, 2 rows/wave).
// ---------------------------------------------------------------------------

constexpr int D  = 256;   // feature / hidden dim
constexpr int C  = 40;    // classes
constexpr int ZP = 64;    // padded z row (fp16 elems) = 128 B

typedef _Float16 h2v    __attribute__((ext_vector_type(2)));
typedef _Float16 h4     __attribute__((ext_vector_type(4)));
typedef _Float16 half8v __attribute__((ext_vector_type(8)));
typedef float    f32x4  __attribute__((ext_vector_type(4)));

struct __align__(8) EdgeCV { int c; float v; };

// ---- CSR build (order-free segment alloc; cnt = real in-edges only) -------

__global__ void k_count(const int* __restrict__ dst, int* __restrict__ cnt,
                        int* __restrict__ eslot, int E) {
    int e = blockIdx.x * blockDim.x + threadIdx.x;
    if (e < E) eslot[e] = atomicAdd(&cnt[dst[e]], 1);
}

// segment alloc + dinv + self-loop edge (at last slot), one pass
__global__ void k_alloc_self(const int* __restrict__ cnt, int* __restrict__ startA,
                             int* __restrict__ cursor, float* __restrict__ dinv,
                             EdgeCV* __restrict__ edges, int N) {
    int i = blockIdx.x * blockDim.x + threadIdx.x;
    if (i < N) {
        int c = cnt[i];
        int s = atomicAdd(cursor, c + 1);
        startA[i] = s;
        float dv = rsqrtf((float)(c + 1));
        dinv[i] = dv;
        EdgeCV ev; ev.c = i; ev.v = dv * dv;
        edges[s + c] = ev;
    }
}

__global__ void k_fill(const int* __restrict__ src, const int* __restrict__ dst,
                       const int* __restrict__ startA, const int* __restrict__ eslot,
                       const float* __restrict__ dinv, EdgeCV* __restrict__ edges, int E) {
    int e = blockIdx.x * blockDim.x + threadIdx.x;
    if (e < E) {
        int s = src[e], d = dst[e];
        EdgeCV ev; ev.c = s; ev.v = dinv[s] * dinv[d];
        edges[startA[d] + eslot[e]] = ev;           // no atomic: slot precomputed
    }
}

// ---- W transpose: W[k][n] fp32 -> Wt[w][n][k] fp16 (3 x 256 x 256) --------

__global__ void k_transW(const float* __restrict__ W0, const float* __restrict__ W1,
                         const float* __restrict__ W2, _Float16* __restrict__ Wt) {
    int n = blockIdx.x;
    int w = blockIdx.y;
    int k = threadIdx.x;
    const float* W = (w == 0) ? W0 : (w == 1) ? W1 : W2;
    Wt[(size_t)w * 65536 + n * 256 + k] = (_Float16)W[k * 256 + n];
}

// ---- MFMA GEMM: Cout_fp16[M x 256] = A[M x 256] @ W (via Wt[n][k] fp16) ---
// SLICED: C written slice-major [4][M][64] (for the sliced SpMM gather).

template <typename TIN, bool SLICED>
__global__ __launch_bounds__(256, 1) void k_gemm_mfma(const TIN* __restrict__ A,
                                                      const _Float16* __restrict__ Wt,
                                                      _Float16* __restrict__ Cout, int M) {
    __shared__ _Float16 wlds[256][72];   // n-major K-strip of 64 (+8 pad)
    const int tid  = threadIdx.x;
    const int lane = tid & 63;
    const int wave = tid >> 6;
    const int l15  = lane & 15;
    const int lk8  = (lane >> 4) * 8;
    const int rowbase = blockIdx.x * 128 + wave * 32;
    const size_t sliceN = (size_t)M * 64;

    half8v a[2][8];
    #pragma unroll
    for (int mt = 0; mt < 2; ++mt) {
        int row = rowbase + mt * 16 + l15;
        bool ok = row < M;
        const TIN* ap = A + (size_t)(ok ? row : 0) * D;
        #pragma unroll
        for (int kk = 0; kk < 8; ++kk) {
            half8v v;
            if constexpr (sizeof(TIN) == 2) {
                v = *(const half8v*)(ap + kk * 32 + lk8);
            } else {
                float4 f0 = *(const float4*)(ap + kk * 32 + lk8);
                float4 f1 = *(const float4*)(ap + kk * 32 + lk8 + 4);
                v[0] = (_Float16)f0.x; v[1] = (_Float16)f0.y;
                v[2] = (_Float16)f0.z; v[3] = (_Float16)f0.w;
                v[4] = (_Float16)f1.x; v[5] = (_Float16)f1.y;
                v[6] = (_Float16)f1.z; v[7] = (_Float16)f1.w;
            }
            if (!ok) {
                half8v zz = {0, 0, 0, 0, 0, 0, 0, 0};
                v = zz;
            }
            a[mt][kk] = v;
        }
    }

    f32x4 acc[2][16] = {};

    #pragma unroll
    for (int s = 0; s < 4; ++s) {       // K strips of 64
        {
            const half8v* srcp = (const half8v*)(Wt + (size_t)tid * D + s * 64);
            #pragma unroll
            for (int cc = 0; cc < 8; ++cc)
                *(half8v*)(&wlds[tid][cc * 8]) = srcp[cc];
        }
        __syncthreads();
        #pragma unroll
        for (int kf = 0; kf < 2; ++kf) {
            const int kk = s * 2 + kf;
            #pragma unroll
            for (int nt = 0; nt < 16; ++nt) {
                half8v b = *(const half8v*)(&wlds[nt * 16 + l15][kf * 32 + lk8]);
                acc[0][nt] = __builtin_amdgcn_mfma_f32_16x16x32_f16(a[0][kk], b, acc[0][nt], 0, 0, 0);
                acc[1][nt] = __builtin_amdgcn_mfma_f32_16x16x32_f16(a[1][kk], b, acc[1][nt], 0, 0, 0);
            }
        }
        __syncthreads();
    }

    const int r0 = (lane >> 4) * 4;
    #pragma unroll
    for (int mt = 0; mt < 2; ++mt) {
        #pragma unroll
        for (int r = 0; r < 4; ++r) {
            int row = rowbase + mt * 16 + r0 + r;
            if (row < M) {
                if constexpr (SLICED) {
                    #pragma unroll
                    for (int nt = 0; nt < 16; ++nt) {
                        int col = nt * 16 + l15;
                        Cout[(size_t)(col >> 6) * sliceN + (size_t)row * 64 + (col & 63)]
                            = (_Float16)acc[mt][nt][r];
                    }
                } else {
                    _Float16* crow = Cout + (size_t)row * D;
                    #pragma unroll
                    for (int nt = 0; nt < 16; ++nt)
                        crow[nt * 16 + l15] = (_Float16)acc[mt][nt][r];
                }
            }
        }
    }
}

// ---- SLICED SpMM (layer 1): grid-y = slice, wave per row, 1 line/edge -----
// t slice-major [4][N][64]; out row-major relu(sum + bias).

__global__ __launch_bounds__(256) void k_spmm_sliced(const _Float16* __restrict__ t,
                                                     const int* __restrict__ startA,
                                                     const int* __restrict__ cnt,
                                                     const EdgeCV* __restrict__ edges,
                                                     const float* __restrict__ bias,
                                                     _Float16* __restrict__ out, int N) {
    int gid   = (int)((blockIdx.x * 256u + threadIdx.x) >> 6);
    int lane  = threadIdx.x & 63;
    int slice = blockIdx.y;
    if (gid >= N) return;
    int start = startA[gid], end = start + cnt[gid] + 1;
    const _Float16* ts = t + (size_t)slice * ((size_t)N * 64);
    float a[8];
    #pragma unroll
    for (int i = 0; i < 8; ++i) a[i] = 0.f;
    int e = start;
    for (; e + 7 < end; e += 8) {
        EdgeCV c[8];
        float x[8];
        #pragma unroll
        for (int i = 0; i < 8; ++i) c[i] = edges[e + i];
        #pragma unroll
        for (int i = 0; i < 8; ++i) x[i] = (float)ts[(size_t)c[i].c * 64 + lane];
        #pragma unroll
        for (int i = 0; i < 8; ++i) a[i] += c[i].v * x[i];
    }
    for (; e < end; ++e) {
        EdgeCV c0 = edges[e];
        a[0] += c0.v * (float)ts[(size_t)c0.c * 64 + lane];
    }
    float acc = ((a[0] + a[1]) + (a[2] + a[3])) + ((a[4] + a[5]) + (a[6] + a[7]));
    float b = bias[slice * 64 + lane];
    out[(size_t)gid * D + slice * 64 + lane] = (_Float16)fmaxf(acc + b, 0.f);
}

// ---- SpMM 256-dim (GCN, r6 form): out = relu(sum + bias), wave/row --------

__global__ __launch_bounds__(256) void k_spmm_relu(const _Float16* __restrict__ h,
                                                   const int* __restrict__ startA,
                                                   const int* __restrict__ cnt,
                                                   const EdgeCV* __restrict__ edges,
                                                   const float* __restrict__ bias,
                                                   _Float16* __restrict__ out, int N) {
    int gid  = (int)((blockIdx.x * 256u + threadIdx.x) >> 6);
    int lane = threadIdx.x & 63;
    if (gid >= N) return;
    int start = startA[gid], end = start + cnt[gid] + 1;
    const h4* hp = (const h4*)h;
    float4 s0 = make_float4(0.f, 0.f, 0.f, 0.f);
    float4 s1 = make_float4(0.f, 0.f, 0.f, 0.f);
    float4 s2 = make_float4(0.f, 0.f, 0.f, 0.f);
    float4 s3 = make_float4(0.f, 0.f, 0.f, 0.f);
    int e = start;
    for (; e + 3 < end; e += 4) {        // 4 independent gathers in flight
        EdgeCV c0 = edges[e],     c1 = edges[e + 1];
        EdgeCV c2 = edges[e + 2], c3 = edges[e + 3];
        h4 x0 = hp[(size_t)c0.c * 64 + lane];
        h4 x1 = hp[(size_t)c1.c * 64 + lane];
        h4 x2 = hp[(size_t)c2.c * 64 + lane];
        h4 x3 = hp[(size_t)c3.c * 64 + lane];
        s0.x += c0.v * (float)x0[0]; s0.y += c0.v * (float)x0[1];
        s0.z += c0.v * (float)x0[2]; s0.w += c0.v * (float)x0[3];
        s1.x += c1.v * (float)x1[0]; s1.y += c1.v * (float)x1[1];
        s1.z += c1.v * (float)x1[2]; s1.w += c1.v * (float)x1[3];
        s2.x += c2.v * (float)x2[0]; s2.y += c2.v * (float)x2[1];
        s2.z += c2.v * (float)x2[2]; s2.w += c2.v * (float)x2[3];
        s3.x += c3.v * (float)x3[0]; s3.y += c3.v * (float)x3[1];
        s3.z += c3.v * (float)x3[2]; s3.w += c3.v * (float)x3[3];
    }
    for (; e < end; ++e) {
        EdgeCV c0 = edges[e];
        h4 x0 = hp[(size_t)c0.c * 64 + lane];
        s0.x += c0.v * (float)x0[0]; s0.y += c0.v * (float)x0[1];
        s0.z += c0.v * (float)x0[2]; s0.w += c0.v * (float)x0[3];
    }
    float4 acc = make_float4(s0.x + s1.x + s2.x + s3.x,
                             s0.y + s1.y + s2.y + s3.y,
                             s0.z + s1.z + s2.z + s3.z,
                             s0.w + s1.w + s2.w + s3.w);
    float4 b = ((const float4*)bias)[lane];
    h4 o;
    o[0] = (_Float16)fmaxf(acc.x + b.x, 0.f);
    o[1] = (_Float16)fmaxf(acc.y + b.y, 0.f);
    o[2] = (_Float16)fmaxf(acc.z + b.z, 0.f);
    o[3] = (_Float16)fmaxf(acc.w + b.w, 0.f);
    ((h4*)out)[(size_t)gid * 64 + lane] = o;
}

// ---- projection z0 = h0 @ fc_w (N x 40), padded to ZP, fp32 acc -----------

__global__ __launch_bounds__(256) void k_z0(const _Float16* __restrict__ h,
                                            const float* __restrict__ fcw,
                                            _Float16* __restrict__ z0, int N) {
    __shared__ float ws[D * C];          // 40 KB
    for (int i = threadIdx.x; i < D * C; i += 256) ws[i] = fcw[i];
    __syncthreads();
    int row = blockIdx.x * 256 + threadIdx.x;
    if (row >= N) return;
    float acc[C] = {};
    const half8v* hr = (const half8v*)(h + (size_t)row * D);
    for (int kq = 0; kq < 32; ++kq) {
        half8v v = hr[kq];
        #pragma unroll
        for (int j = 0; j < 8; ++j) {
            float hv = (float)v[j];
            #pragma unroll
            for (int c = 0; c < C; ++c) acc[c] += hv * ws[(kq * 8 + j) * C + c];
        }
    }
    h2v* zr = (h2v*)(z0 + (size_t)row * ZP);
    #pragma unroll
    for (int c = 0; c < 20; ++c) {
        h2v o; o[0] = (_Float16)acc[2 * c]; o[1] = (_Float16)acc[2 * c + 1];
        zr[c] = o;
    }
    h2v zz = {(_Float16)0.f, (_Float16)0.f};
    #pragma unroll
    for (int c = 20; c < 32; ++c) zr[c] = zz;   // zero the pad
}

// ---- SpMM 40-dim padded (APPNP): 2 rows/wave, 8-deep gather pipeline ------

__global__ __launch_bounds__(256) void k_spmm40(const _Float16* __restrict__ z,
                                                const int* __restrict__ startA,
                                                const int* __restrict__ cnt,
                                                const EdgeCV* __restrict__ edges,
                                                const _Float16* __restrict__ z0,
                                                _Float16* __restrict__ out, int N) {
    int wid  = (int)((blockIdx.x * 256u + threadIdx.x) >> 6);
    int lane = threadIdx.x & 63;
    int p    = lane >> 5;                 // half-wave -> row parity
    int l5   = lane & 31;
    int row  = wid * 2 + p;
    if (row >= N) return;
    int start = startA[row], end = start + cnt[row] + 1;
    const h2v* zp = (const h2v*)z;        // row stride ZP/2 = 32 h2v
    float ax[8], ay[8];
    #pragma unroll
    for (int i = 0; i < 8; ++i) { ax[i] = 0.f; ay[i] = 0.f; }
    int e = start;
    for (; e + 7 < end; e += 8) {
        EdgeCV c[8];
        h2v x[8];
        #pragma unroll
        for (int i = 0; i < 8; ++i) c[i] = edges[e + i];
        #pragma unroll
        for (int i = 0; i < 8; ++i) x[i] = zp[(size_t)c[i].c * 32 + l5];
        #pragma unroll
        for (int i = 0; i < 8; ++i) {
            ax[i] += c[i].v * (float)x[i][0];
            ay[i] += c[i].v * (float)x[i][1];
        }
    }
    for (; e < end; ++e) {
        EdgeCV c0 = edges[e];
        h2v x0 = zp[(size_t)c0.c * 32 + l5];
        ax[0] += c0.v * (float)x0[0]; ay[0] += c0.v * (float)x0[1];
    }
    float axs = ((ax[0] + ax[1]) + (ax[2] + ax[3])) + ((ax[4] + ax[5]) + (ax[6] + ax[7]));
    float ays = ((ay[0] + ay[1]) + (ay[2] + ay[3])) + ((ay[4] + ay[5]) + (ay[6] + ay[7]));
    h2v zz = ((const h2v*)z0)[(size_t)row * 32 + l5];
    axs = 0.9f * axs + 0.1f * (float)zz[0];
    ays = 0.9f * ays + 0.1f * (float)zz[1];
    h2v o; o[0] = (_Float16)axs; o[1] = (_Float16)ays;
    ((h2v*)out)[(size_t)row * 32 + l5] = o;
}

// ---- final: out = log_softmax(z + fcb) ------------------------------------

__global__ __launch_bounds__(256) void k_logsm(const _Float16* __restrict__ z,
                                               const float* __restrict__ fcb,
                                               float* __restrict__ out, int N) {
    __shared__ float bs[C];
    for (int i = threadIdx.x; i < C; i += 256) bs[i] = fcb[i];
    __syncthreads();
    int row = blockIdx.x * 256 + threadIdx.x;
    if (row >= N) return;
    float v[C];
    const h2v* zr = (const h2v*)(z + (size_t)row * ZP);
    #pragma unroll
    for (int c = 0; c < 20; ++c) {
        h2v t = zr[c];
        v[2 * c]     = (float)t[0] + bs[2 * c];
        v[2 * c + 1] = (float)t[1] + bs[2 * c + 1];
    }
    float m = v[0];
    #pragma unroll
    for (int c = 1; c < C; ++c) m = fmaxf(m, v[c]);
    float s = 0.f;
    #pragma unroll
    for (int c = 0; c < C; ++c) s += expf(v[c] - m);
    float lse = logf(s) + m;
    float* orow = out + (size_t)row * C;
    #pragma unroll
    for (int c = 0; c < C; ++c) orow[c] = v[c] - lse;
}

// ---------------------------------------------------------------------------

extern "C" void kernel_launch(void* const* d_in, const int* in_sizes, int n_in,
                              void* d_out, int out_size, void* d_ws, size_t ws_size,
                              hipStream_t stream) {
    const float* x   = (const float*)d_in[0];
    const int*   ei  = (const int*)d_in[1];
    const float* w1  = (const float*)d_in[2];
    const float* b1  = (const float*)d_in[3];
    const float* w2  = (const float*)d_in[4];
    const float* b2  = (const float*)d_in[5];
    const float* w3  = (const float*)d_in[6];
    const float* b3  = (const float*)d_in[7];
    const float* fcw = (const float*)d_in[8];
    const float* fcb = (const float*)d_in[9];
    float* out = (float*)d_out;

    const int N = in_sizes[0] / D;
    const int E = in_sizes[1] / 2;
    const int* srcArr = ei;
    const int* dstArr = ei + E;

    char* wsp = (char*)d_ws;
    size_t off = 0;
    auto take = [&](size_t bytes) -> void* {
        void* p = wsp + off;
        off = (off + bytes + 255) & ~(size_t)255;
        return p;
    };
    int*       cnt    = (int*)take((size_t)N * 4);
    int*       startA = (int*)take((size_t)N * 4);
    int*       eslot  = (int*)take((size_t)E * 4);
    int*       cursor = (int*)take(256);
    float*     dinv   = (float*)take((size_t)N * 4);
    EdgeCV*    edges  = (EdgeCV*)take((size_t)(E + N) * 8);
    _Float16*  bufA   = (_Float16*)take((size_t)N * D * 2);
    _Float16*  bufB   = (_Float16*)take((size_t)N * D * 2);
    _Float16*  bufC   = (_Float16*)take((size_t)N * D * 2);
    _Float16*  Wt     = (_Float16*)take((size_t)3 * D * D * 2);
    _Float16*  z0w    = (_Float16*)take((size_t)N * ZP * 2);
    _Float16*  zA     = (_Float16*)take((size_t)N * ZP * 2);
    _Float16*  zB     = (_Float16*)take((size_t)N * ZP * 2);
    (void)ws_size;

    dim3 b256(256);
    int gN = (N + 255) / 256;
    int gE = (E + 255) / 256;

    // CSR build (no scan, no fill-atomics)
    hipMemsetAsync(cursor, 0, 4, stream);
    hipMemsetAsync(cnt, 0, (size_t)N * 4, stream);
    k_count<<<gE, b256, 0, stream>>>(dstArr, cnt, eslot, E);
    k_alloc_self<<<gN, b256, 0, stream>>>(cnt, startA, cursor, dinv, edges, N);
    k_fill<<<gE, b256, 0, stream>>>(srcArr, dstArr, startA, eslot, dinv, edges, E);

    // weight transposes (fp32 -> fp16, n-major)
    dim3 tg(256, 3);
    k_transW<<<tg, b256, 0, stream>>>(w1, w2, w3, Wt);

    dim3 gg((N + 127) / 128);
    int spBlocks   = (N + 3) / 4;      // wave per row (256-dim)
    int sp40Blocks = (N + 7) / 8;      // 2 rows per wave (40-dim padded)
    dim3 slicedGrid((N + 3) / 4, 4);   // wave per (row, slice)

    // layer 1: GEMM (sliced C) -> sliced SpMM (experiment)
    k_gemm_mfma<float, true><<<gg, b256, 0, stream>>>(x, Wt, bufB, N);
    k_spmm_sliced<<<slicedGrid, b256, 0, stream>>>(bufB, startA, cnt, edges, b1, bufA, N);
    // layers 2,3: r6-form
    k_gemm_mfma<_Float16, false><<<gg, b256, 0, stream>>>(bufA, Wt + 65536, bufB, N);
    k_spmm_relu<<<spBlocks, b256, 0, stream>>>(bufB, startA, cnt, edges, b2, bufA, N);
    k_gemm_mfma<_Float16, false><<<gg, b256, 0, stream>>>(bufA, Wt + 131072, bufB, N);
    k_spmm_relu<<<spBlocks, b256, 0, stream>>>(bufB, startA, cnt, edges, b3, bufC, N);  // h0

    // project: z0 = h0 @ fc_w  (bias added at the end), padded rows
    k_z0<<<gN, b256, 0, stream>>>(bufC, fcw, z0w, N);

    // APPNP on padded 40-dim z: z <- 0.9 * A_hat z + 0.1 * z0
    const _Float16* zc = z0w;
    _Float16* zn = zA;
    for (int it = 0; it < 10; ++it) {
        k_spmm40<<<sp40Blocks, b256, 0, stream>>>(zc, startA, cnt, edges, z0w, zn, N);
        zc = zn;
        zn = (zn == zA) ? zB : zA;
    }

    // final: log_softmax(z + fcb)
    k_logsm<<<gN, b256, 0, stream>>>(zc, fcb, out, N);
}

// Round 9
// 1942.763 us; speedup vs baseline: 1.2365x; 1.0885x over previous
//
#include <hip/hip_runtime.h>
#include <math.h>

// ---------------------------------------------------------------------------
// APPNP + 3-layer GCN on MI355X.
// Round 9 (consolidation after slicing experiment falsified):
//  (a) Layer 1 reverted to row-major GEMM + standard spmm_relu (sliced variant
//      measured 391 us vs 227 us: concurrent slices defeat L2 residency and
//      quadruple issue). All 3 GCN layers uniform again.
//  (b) z0 projection MFMA-ized (100K x 256 x 40 GEMM): FcT[48][256] fp16
//      staged once (24 KB, L2-resident, read direct - no LDS), z0 pad zeroed
//      via memset. Replaces ~40 us scalar-VALU k_z0 with ~12 us stream kernel.
//  (c) CSR (eslot, atomic-free fill), spmm40 (8-unroll, 2 rows/wave), logsm
//      carried unchanged from r8.
// Known floors: 256-dim propagate 227 us (random-line service ceiling,
// 4 lines/edge); APPNP needs exactly 10 mat-vecs (degree-10 polynomial).
// ---------------------------------------------------------------------------

constexpr int D  = 256;   // feature / hidden dim
constexpr int C  = 40;    // classes
constexpr int ZP = 64;    // padded z row (fp16 elems) = 128 B

typedef _Float16 h2v    __attribute__((ext_vector_type(2)));
typedef _Float16 h4     __attribute__((ext_vector_type(4)));
typedef _Float16 half8v __attribute__((ext_vector_type(8)));
typedef float    f32x4  __attribute__((ext_vector_type(4)));

struct __align__(8) EdgeCV { int c; float v; };

// ---- CSR build (order-free segment alloc; cnt = real in-edges only) -------

__global__ void k_count(const int* __restrict__ dst, int* __restrict__ cnt,
                        int* __restrict__ eslot, int E) {
    int e = blockIdx.x * blockDim.x + threadIdx.x;
    if (e < E) eslot[e] = atomicAdd(&cnt[dst[e]], 1);
}

// segment alloc + dinv + self-loop edge (at last slot), one pass
__global__ void k_alloc_self(const int* __restrict__ cnt, int* __restrict__ startA,
                             int* __restrict__ cursor, float* __restrict__ dinv,
                             EdgeCV* __restrict__ edges, int N) {
    int i = blockIdx.x * blockDim.x + threadIdx.x;
    if (i < N) {
        int c = cnt[i];
        int s = atomicAdd(cursor, c + 1);
        startA[i] = s;
        float dv = rsqrtf((float)(c + 1));
        dinv[i] = dv;
        EdgeCV ev; ev.c = i; ev.v = dv * dv;
        edges[s + c] = ev;
    }
}

__global__ void k_fill(const int* __restrict__ src, const int* __restrict__ dst,
                       const int* __restrict__ startA, const int* __restrict__ eslot,
                       const float* __restrict__ dinv, EdgeCV* __restrict__ edges, int E) {
    int e = blockIdx.x * blockDim.x + threadIdx.x;
    if (e < E) {
        int s = src[e], d = dst[e];
        EdgeCV ev; ev.c = s; ev.v = dinv[s] * dinv[d];
        edges[startA[d] + eslot[e]] = ev;           // no atomic: slot precomputed
    }
}

// ---- W transpose: W[k][n] fp32 -> Wt[w][n][k] fp16 (3 x 256 x 256) --------

__global__ void k_transW(const float* __restrict__ W0, const float* __restrict__ W1,
                         const float* __restrict__ W2, _Float16* __restrict__ Wt) {
    int n = blockIdx.x;
    int w = blockIdx.y;
    int k = threadIdx.x;
    const float* W = (w == 0) ? W0 : (w == 1) ? W1 : W2;
    Wt[(size_t)w * 65536 + n * 256 + k] = (_Float16)W[k * 256 + n];
}

// fc_w [256][40] fp32 -> FcT[48][256] fp16 (rows 40..47 zero)
__global__ void k_transFc(const float* __restrict__ fcw, _Float16* __restrict__ FcT) {
    int n = blockIdx.x;          // 0..47
    int k = threadIdx.x;         // 0..255
    FcT[n * 256 + k] = (n < C) ? (_Float16)fcw[k * C + n] : (_Float16)0.f;
}

// ---- MFMA GEMM: Cout_fp16[M x 256] = A[M x 256] @ W (via Wt[n][k] fp16) ---
// block = 256 threads (4 waves), 128 rows/block, full N=256, fp32 accumulate.
// Fragment map (learn_hip m89/m92 verified):
//   A frag: lane l holds A[l&15][8*(l>>4)+j], j=0..7 (contiguous k)
//   B frag: lane l holds B[8*(l>>4)+j][l&15]  == Wt[l&15][8*(l>>4)+j]
//   C/D:    lane l reg r -> row 4*(l>>4)+r, col l&15

template <typename TIN>
__global__ __launch_bounds__(256, 1) void k_gemm_mfma(const TIN* __restrict__ A,
                                                      const _Float16* __restrict__ Wt,
                                                      _Float16* __restrict__ Cout, int M) {
    __shared__ _Float16 wlds[256][72];   // n-major K-strip of 64 (+8 pad)
    const int tid  = threadIdx.x;
    const int lane = tid & 63;
    const int wave = tid >> 6;
    const int l15  = lane & 15;
    const int lk8  = (lane >> 4) * 8;
    const int rowbase = blockIdx.x * 128 + wave * 32;

    half8v a[2][8];
    #pragma unroll
    for (int mt = 0; mt < 2; ++mt) {
        int row = rowbase + mt * 16 + l15;
        bool ok = row < M;
        const TIN* ap = A + (size_t)(ok ? row : 0) * D;
        #pragma unroll
        for (int kk = 0; kk < 8; ++kk) {
            half8v v;
            if constexpr (sizeof(TIN) == 2) {
                v = *(const half8v*)(ap + kk * 32 + lk8);
            } else {
                float4 f0 = *(const float4*)(ap + kk * 32 + lk8);
                float4 f1 = *(const float4*)(ap + kk * 32 + lk8 + 4);
                v[0] = (_Float16)f0.x; v[1] = (_Float16)f0.y;
                v[2] = (_Float16)f0.z; v[3] = (_Float16)f0.w;
                v[4] = (_Float16)f1.x; v[5] = (_Float16)f1.y;
                v[6] = (_Float16)f1.z; v[7] = (_Float16)f1.w;
            }
            if (!ok) {
                half8v zz = {0, 0, 0, 0, 0, 0, 0, 0};
                v = zz;
            }
            a[mt][kk] = v;
        }
    }

    f32x4 acc[2][16] = {};

    #pragma unroll
    for (int s = 0; s < 4; ++s) {       // K strips of 64
        {
            const half8v* srcp = (const half8v*)(Wt + (size_t)tid * D + s * 64);
            #pragma unroll
            for (int cc = 0; cc < 8; ++cc)
                *(half8v*)(&wlds[tid][cc * 8]) = srcp[cc];
        }
        __syncthreads();
        #pragma unroll
        for (int kf = 0; kf < 2; ++kf) {
            const int kk = s * 2 + kf;
            #pragma unroll
            for (int nt = 0; nt < 16; ++nt) {
                half8v b = *(const half8v*)(&wlds[nt * 16 + l15][kf * 32 + lk8]);
                acc[0][nt] = __builtin_amdgcn_mfma_f32_16x16x32_f16(a[0][kk], b, acc[0][nt], 0, 0, 0);
                acc[1][nt] = __builtin_amdgcn_mfma_f32_16x16x32_f16(a[1][kk], b, acc[1][nt], 0, 0, 0);
            }
        }
        __syncthreads();
    }

    const int r0 = (lane >> 4) * 4;
    #pragma unroll
    for (int mt = 0; mt < 2; ++mt) {
        #pragma unroll
        for (int r = 0; r < 4; ++r) {
            int row = rowbase + mt * 16 + r0 + r;
            if (row < M) {
                _Float16* crow = Cout + (size_t)row * D;
                #pragma unroll
                for (int nt = 0; nt < 16; ++nt)
                    crow[nt * 16 + l15] = (_Float16)acc[mt][nt][r];
            }
        }
    }
}

// ---- MFMA z0: z0[M x ZP] = h0[M x 256] @ fc_w (via FcT[48][256] fp16) -----
// 3 n-tiles (48 cols, writes only cols < 40; pad pre-zeroed by memset).
// FcT is 24 KB -> L2-resident; B-frags read direct from global.

__global__ __launch_bounds__(256, 1) void k_z0_mfma(const _Float16* __restrict__ h,
                                                    const _Float16* __restrict__ FcT,
                                                    _Float16* __restrict__ z0, int M) {
    const int tid  = threadIdx.x;
    const int lane = tid & 63;
    const int wave = tid >> 6;
    const int l15  = lane & 15;
    const int lk8  = (lane >> 4) * 8;
    const int rowbase = blockIdx.x * 128 + wave * 32;

    half8v a[2][8];
    #pragma unroll
    for (int mt = 0; mt < 2; ++mt) {
        int row = rowbase + mt * 16 + l15;
        bool ok = row < M;
        const _Float16* ap = h + (size_t)(ok ? row : 0) * D;
        #pragma unroll
        for (int kk = 0; kk < 8; ++kk) {
            half8v v = *(const half8v*)(ap + kk * 32 + lk8);
            if (!ok) { half8v zz = {0,0,0,0,0,0,0,0}; v = zz; }
            a[mt][kk] = v;
        }
    }

    f32x4 acc[2][3] = {};
    #pragma unroll
    for (int kk = 0; kk < 8; ++kk) {
        #pragma unroll
        for (int nt = 0; nt < 3; ++nt) {
            half8v b = *(const half8v*)(FcT + (size_t)(nt * 16 + l15) * D + kk * 32 + lk8);
            acc[0][nt] = __builtin_amdgcn_mfma_f32_16x16x32_f16(a[0][kk], b, acc[0][nt], 0, 0, 0);
            acc[1][nt] = __builtin_amdgcn_mfma_f32_16x16x32_f16(a[1][kk], b, acc[1][nt], 0, 0, 0);
        }
    }

    const int r0 = (lane >> 4) * 4;
    #pragma unroll
    for (int mt = 0; mt < 2; ++mt) {
        #pragma unroll
        for (int r = 0; r < 4; ++r) {
            int row = rowbase + mt * 16 + r0 + r;
            if (row < M) {
                _Float16* zrow = z0 + (size_t)row * ZP;
                #pragma unroll
                for (int nt = 0; nt < 3; ++nt) {
                    int col = nt * 16 + l15;
                    if (col < C) zrow[col] = (_Float16)acc[mt][nt][r];
                }
            }
        }
    }
}

// ---- SpMM 256-dim (GCN): out = relu(sum + bias), wave/row, 4-unroll -------

__global__ __launch_bounds__(256) void k_spmm_relu(const _Float16* __restrict__ h,
                                                   const int* __restrict__ startA,
                                                   const int* __restrict__ cnt,
                                                   const EdgeCV* __restrict__ edges,
                                                   const float* __restrict__ bias,
                                                   _Float16* __restrict__ out, int N) {
    int gid  = (int)((blockIdx.x * 256u + threadIdx.x) >> 6);
    int lane = threadIdx.x & 63;
    if (gid >= N) return;
    int start = startA[gid], end = start + cnt[gid] + 1;
    const h4* hp = (const h4*)h;
    float4 s0 = make_float4(0.f, 0.f, 0.f, 0.f);
    float4 s1 = make_float4(0.f, 0.f, 0.f, 0.f);
    float4 s2 = make_float4(0.f, 0.f, 0.f, 0.f);
    float4 s3 = make_float4(0.f, 0.f, 0.f, 0.f);
    int e = start;
    for (; e + 3 < end; e += 4) {        // 4 independent gathers in flight
        EdgeCV c0 = edges[e],     c1 = edges[e + 1];
        EdgeCV c2 = edges[e + 2], c3 = edges[e + 3];
        h4 x0 = hp[(size_t)c0.c * 64 + lane];
        h4 x1 = hp[(size_t)c1.c * 64 + lane];
        h4 x2 = hp[(size_t)c2.c * 64 + lane];
        h4 x3 = hp[(size_t)c3.c * 64 + lane];
        s0.x += c0.v * (float)x0[0]; s0.y += c0.v * (float)x0[1];
        s0.z += c0.v * (float)x0[2]; s0.w += c0.v * (float)x0[3];
        s1.x += c1.v * (float)x1[0]; s1.y += c1.v * (float)x1[1];
        s1.z += c1.v * (float)x1[2]; s1.w += c1.v * (float)x1[3];
        s2.x += c2.v * (float)x2[0]; s2.y += c2.v * (float)x2[1];
        s2.z += c2.v * (float)x2[2]; s2.w += c2.v * (float)x2[3];
        s3.x += c3.v * (float)x3[0]; s3.y += c3.v * (float)x3[1];
        s3.z += c3.v * (float)x3[2]; s3.w += c3.v * (float)x3[3];
    }
    for (; e < end; ++e) {
        EdgeCV c0 = edges[e];
        h4 x0 = hp[(size_t)c0.c * 64 + lane];
        s0.x += c0.v * (float)x0[0]; s0.y += c0.v * (float)x0[1];
        s0.z += c0.v * (float)x0[2]; s0.w += c0.v * (float)x0[3];
    }
    float4 acc = make_float4(s0.x + s1.x + s2.x + s3.x,
                             s0.y + s1.y + s2.y + s3.y,
                             s0.z + s1.z + s2.z + s3.z,
                             s0.w + s1.w + s2.w + s3.w);
    float4 b = ((const float4*)bias)[lane];
    h4 o;
    o[0] = (_Float16)fmaxf(acc.x + b.x, 0.f);
    o[1] = (_Float16)fmaxf(acc.y + b.y, 0.f);
    o[2] = (_Float16)fmaxf(acc.z + b.z, 0.f);
    o[3] = (_Float16)fmaxf(acc.w + b.w, 0.f);
    ((h4*)out)[(size_t)gid * 64 + lane] = o;
}

// ---- SpMM 40-dim padded (APPNP): 2 rows/wave, 8-deep gather pipeline ------

__global__ __launch_bounds__(256) void k_spmm40(const _Float16* __restrict__ z,
                                                const int* __restrict__ startA,
                                                const int* __restrict__ cnt,
                                                const EdgeCV* __restrict__ edges,
                                                const _Float16* __restrict__ z0,
                                                _Float16* __restrict__ out, int N) {
    int wid  = (int)((blockIdx.x * 256u + threadIdx.x) >> 6);
    int lane = threadIdx.x & 63;
    int p    = lane >> 5;                 // half-wave -> row parity
    int l5   = lane & 31;
    int row  = wid * 2 + p;
    if (row >= N) return;
    int start = startA[row], end = start + cnt[row] + 1;
    const h2v* zp = (const h2v*)z;        // row stride ZP/2 = 32 h2v
    float ax[8], ay[8];
    #pragma unroll
    for (int i = 0; i < 8; ++i) { ax[i] = 0.f; ay[i] = 0.f; }
    int e = start;
    for (; e + 7 < end; e += 8) {
        EdgeCV c[8];
        h2v x[8];
        #pragma unroll
        for (int i = 0; i < 8; ++i) c[i] = edges[e + i];
        #pragma unroll
        for (int i = 0; i < 8; ++i) x[i] = zp[(size_t)c[i].c * 32 + l5];
        #pragma unroll
        for (int i = 0; i < 8; ++i) {
            ax[i] += c[i].v * (float)x[i][0];
            ay[i] += c[i].v * (float)x[i][1];
        }
    }
    for (; e < end; ++e) {
        EdgeCV c0 = edges[e];
        h2v x0 = zp[(size_t)c0.c * 32 + l5];
        ax[0] += c0.v * (float)x0[0]; ay[0] += c0.v * (float)x0[1];
    }
    float axs = ((ax[0] + ax[1]) + (ax[2] + ax[3])) + ((ax[4] + ax[5]) + (ax[6] + ax[7]));
    float ays = ((ay[0] + ay[1]) + (ay[2] + ay[3])) + ((ay[4] + ay[5]) + (ay[6] + ay[7]));
    h2v zz = ((const h2v*)z0)[(size_t)row * 32 + l5];
    axs = 0.9f * axs + 0.1f * (float)zz[0];
    ays = 0.9f * ays + 0.1f * (float)zz[1];
    h2v o; o[0] = (_Float16)axs; o[1] = (_Float16)ays;
    ((h2v*)out)[(size_t)row * 32 + l5] = o;
}

// ---- final: out = log_softmax(z + fcb) ------------------------------------

__global__ __launch_bounds__(256) void k_logsm(const _Float16* __restrict__ z,
                                               const float* __restrict__ fcb,
                                               float* __restrict__ out, int N) {
    __shared__ float bs[C];
    for (int i = threadIdx.x; i < C; i += 256) bs[i] = fcb[i];
    __syncthreads();
    int row = blockIdx.x * 256 + threadIdx.x;
    if (row >= N) return;
    float v[C];
    const h2v* zr = (const h2v*)(z + (size_t)row * ZP);
    #pragma unroll
    for (int c = 0; c < 20; ++c) {
        h2v t = zr[c];
        v[2 * c]     = (float)t[0] + bs[2 * c];
        v[2 * c + 1] = (float)t[1] + bs[2 * c + 1];
    }
    float m = v[0];
    #pragma unroll
    for (int c = 1; c < C; ++c) m = fmaxf(m, v[c]);
    float s = 0.f;
    #pragma unroll
    for (int c = 0; c < C; ++c) s += expf(v[c] - m);
    float lse = logf(s) + m;
    float* orow = out + (size_t)row * C;
    #pragma unroll
    for (int c = 0; c < C; ++c) orow[c] = v[c] - lse;
}

// ---------------------------------------------------------------------------

extern "C" void kernel_launch(void* const* d_in, const int* in_sizes, int n_in,
                              void* d_out, int out_size, void* d_ws, size_t ws_size,
                              hipStream_t stream) {
    const float* x   = (const float*)d_in[0];
    const int*   ei  = (const int*)d_in[1];
    const float* w1  = (const float*)d_in[2];
    const float* b1  = (const float*)d_in[3];
    const float* w2  = (const float*)d_in[4];
    const float* b2  = (const float*)d_in[5];
    const float* w3  = (const float*)d_in[6];
    const float* b3  = (const float*)d_in[7];
    const float* fcw = (const float*)d_in[8];
    const float* fcb = (const float*)d_in[9];
    float* out = (float*)d_out;

    const int N = in_sizes[0] / D;
    const int E = in_sizes[1] / 2;
    const int* srcArr = ei;
    const int* dstArr = ei + E;

    char* wsp = (char*)d_ws;
    size_t off = 0;
    auto take = [&](size_t bytes) -> void* {
        void* p = wsp + off;
        off = (off + bytes + 255) & ~(size_t)255;
        return p;
    };
    int*       cnt    = (int*)take((size_t)N * 4);
    int*       startA = (int*)take((size_t)N * 4);
    int*       eslot  = (int*)take((size_t)E * 4);
    int*       cursor = (int*)take(256);
    float*     dinv   = (float*)take((size_t)N * 4);
    EdgeCV*    edges  = (EdgeCV*)take((size_t)(E + N) * 8);
    _Float16*  bufA   = (_Float16*)take((size_t)N * D * 2);
    _Float16*  bufB   = (_Float16*)take((size_t)N * D * 2);
    _Float16*  bufC   = (_Float16*)take((size_t)N * D * 2);
    _Float16*  Wt     = (_Float16*)take((size_t)3 * D * D * 2);
    _Float16*  FcT    = (_Float16*)take((size_t)48 * D * 2);
    _Float16*  z0w    = (_Float16*)take((size_t)N * ZP * 2);
    _Float16*  zA     = (_Float16*)take((size_t)N * ZP * 2);
    _Float16*  zB     = (_Float16*)take((size_t)N * ZP * 2);
    (void)ws_size;

    dim3 b256(256);
    int gN = (N + 255) / 256;
    int gE = (E + 255) / 256;

    // CSR build (no scan, no fill-atomics)
    hipMemsetAsync(cursor, 0, 4, stream);
    hipMemsetAsync(cnt, 0, (size_t)N * 4, stream);
    hipMemsetAsync(z0w, 0, (size_t)N * ZP * 2, stream);   // pad cols stay zero
    k_count<<<gE, b256, 0, stream>>>(dstArr, cnt, eslot, E);
    k_alloc_self<<<gN, b256, 0, stream>>>(cnt, startA, cursor, dinv, edges, N);
    k_fill<<<gE, b256, 0, stream>>>(srcArr, dstArr, startA, eslot, dinv, edges, E);

    // weight transposes (fp32 -> fp16, n-major)
    dim3 tg(256, 3);
    k_transW<<<tg, b256, 0, stream>>>(w1, w2, w3, Wt);
    k_transFc<<<48, b256, 0, stream>>>(fcw, FcT);

    dim3 gg((N + 127) / 128);
    int spBlocks   = (N + 3) / 4;      // wave per row (256-dim)
    int sp40Blocks = (N + 7) / 8;      // 2 rows per wave (40-dim padded)

    // GCN layers (bias+relu fused into SpMM epilogue)
    k_gemm_mfma<float><<<gg, b256, 0, stream>>>(x, Wt, bufB, N);
    k_spmm_relu<<<spBlocks, b256, 0, stream>>>(bufB, startA, cnt, edges, b1, bufA, N);
    k_gemm_mfma<_Float16><<<gg, b256, 0, stream>>>(bufA, Wt + 65536, bufB, N);
    k_spmm_relu<<<spBlocks, b256, 0, stream>>>(bufB, startA, cnt, edges, b2, bufA, N);
    k_gemm_mfma<_Float16><<<gg, b256, 0, stream>>>(bufA, Wt + 131072, bufB, N);
    k_spmm_relu<<<spBlocks, b256, 0, stream>>>(bufB, startA, cnt, edges, b3, bufC, N);  // h0

    // project: z0 = h0 @ fc_w  (MFMA; bias added at the end), padded rows
    k_z0_mfma<<<gg, b256, 0, stream>>>(bufC, FcT, z0w, N);

    // APPNP on padded 40-dim z: z <- 0.9 * A_hat z + 0.1 * z0
    const _Float16* zc = z0w;
    _Float16* zn = zA;
    for (int it = 0; it < 10; ++it) {
        k_spmm40<<<sp40Blocks, b256, 0, stream>>>(zc, startA, cnt, edges, z0w, zn, N);
        zc = zn;
        zn = (zn == zA) ? zB : zA;
    }

    // final: log_softmax(z + fcb)
    k_logsm<<<gN, b256, 0, stream>>>(zc, fcb, out, N);
}